// Round 2
// baseline (4861.649 us; speedup 1.0000x reference)
//
#include <hip/hip_runtime.h>

// V=16000 E=512 H=512 L=2 S=128 T=128 B=64; gate dim 4H=2048
// Unified design: both LSTM layers do a K=1024 concat GEMM per step:
//   gates[b][4H] = [x_t | h_{t-1}] @ [Wih | Whh]^T + (bih+bhh)
// Histories per layer: 257 slots of [64][512] fp16. Slot g = state at time g:
//   g=0 zeros (enc init), g=1..128 encoder outputs, g=129..255 decoder outputs,
//   slot 256 zero pad for the logits GEMM's 8192-row tile reads.

typedef __attribute__((ext_vector_type(8))) short v8s;
typedef __attribute__((ext_vector_type(4))) short v4s;
typedef __attribute__((ext_vector_type(8))) _Float16 v8h;
typedef __attribute__((ext_vector_type(4))) float v4f;

#define AS1 __attribute__((address_space(1)))
#define AS3 __attribute__((address_space(3)))

__device__ __forceinline__ short f2h(float x) {
  _Float16 h = (_Float16)x;
  return __builtin_bit_cast(short, h);
}
__device__ __forceinline__ void gload16(const void* g, void* l) {
  __builtin_amdgcn_global_load_lds((const AS1 void*)g, (AS3 void*)l, 16, 0, 0);
}
__device__ __forceinline__ float sigf(float x) { return 1.f / (1.f + __expf(-x)); }
__device__ __forceinline__ float tanhfast(float x) { return 2.f / (1.f + __expf(-2.f * x)) - 1.f; }

// ---------- weight convert fp32->fp16 + gate reorder (i,f,g,o interleave per unit)
__global__ void conv_w(const float* __restrict__ in, short* __restrict__ out,
                       int rows, int ldo, int coloff, int reorder) {
  int i = blockIdx.x * 256 + threadIdx.x;       // one float4 per thread
  if (i >= rows * 128) return;                  // K=512 -> 128 quads per row
  int r = i >> 7, k4 = (i & 127) * 4;
  int rr = reorder ? ((r & 511) * 4 + (r >> 9)) : r;
  float4 v = *(const float4*)(in + (size_t)r * 512 + k4);
  v4s s; s[0] = f2h(v.x); s[1] = f2h(v.y); s[2] = f2h(v.z); s[3] = f2h(v.w);
  *(v4s*)(out + (size_t)rr * ldo + coloff + k4) = s;
}

__global__ void conv_b(const float* __restrict__ a, const float* __restrict__ b,
                       float* __restrict__ o) {
  int r = blockIdx.x * 256 + threadIdx.x;
  if (r < 2048) o[(r & 511) * 4 + (r >> 9)] = a[r] + b[r];
}

// ---------- embedding gather to fp16, rows >= nvalid get zeros
__global__ void embed_k(const int* __restrict__ ids, const float* __restrict__ emb,
                        short* __restrict__ out, int nvalid) {
  int row = blockIdx.x;
  int e = threadIdx.x * 2;
  float2 v = make_float2(0.f, 0.f);
  if (row < nvalid) {
    int id = ids[row];
    v = *(const float2*)(emb + (size_t)id * 512 + e);
  }
  unsigned pack = ((unsigned)(unsigned short)f2h(v.y) << 16) | (unsigned short)f2h(v.x);
  *(unsigned*)(out + (size_t)row * 512 + e) = pack;
}

__global__ void zero_k(short* p, int n) {
  int i = blockIdx.x * 256 + threadIdx.x;
  if (i < n) p[i] = 0;
}

// ---------- GEMM: C[M,N] = A[M,K] * B[N,K]^T (+bias), 128x128 tile, BK=64, fp16
#define GF_BIAS 2
#define GF_GUARDM 4

__global__ __launch_bounds__(256, 2) void gemm_bt(
    const short* __restrict__ Am, const short* __restrict__ Bm,
    const float* __restrict__ bias, float* __restrict__ Cm,
    int M, int N, int K, int ldc, int flags) {
  __shared__ short lA[128 * 64];
  __shared__ short lB[128 * 64];
  const int tid = threadIdx.x, lane = tid & 63, wave = tid >> 6;
  const int wm = wave >> 1, wn = wave & 1;
  const int tm = blockIdx.y, tn = blockIdx.x;
  v4f acc[4][4] = {};
  const short* Abase = Am + (size_t)tm * 128 * K;
  const short* Bbase = Bm + (size_t)tn * 128 * K;

  for (int kt = 0; kt < K; kt += 64) {
    __syncthreads();
#pragma unroll
    for (int i2 = 0; i2 < 4; ++i2) {
      int c = (wave * 4 + i2) * 64 + lane;    // 16B chunk id, 1024 per tile
      int row = c >> 3, ch = c & 7;
      int sch = ch ^ (row & 7);               // inverse swizzle on global source
      gload16(Abase + (size_t)row * K + kt + sch * 8, (char*)lA + (wave * 4 + i2) * 1024);
      gload16(Bbase + (size_t)row * K + kt + sch * 8, (char*)lB + (wave * 4 + i2) * 1024);
    }
    asm volatile("s_waitcnt vmcnt(0)" ::: "memory");
    __syncthreads();
#pragma unroll
    for (int kc = 0; kc < 2; ++kc) {
      v8h af[4], bh[4];
#pragma unroll
      for (int mt = 0; mt < 4; ++mt) {
        int row = wm * 64 + mt * 16 + (lane & 15);
        af[mt] = *(const v8h*)((const char*)lA + row * 128 +
                               ((kc * 64 + (lane >> 4) * 16) ^ ((row & 7) << 4)));
      }
#pragma unroll
      for (int nt = 0; nt < 4; ++nt) {
        int row = wn * 64 + nt * 16 + (lane & 15);
        bh[nt] = *(const v8h*)((const char*)lB + row * 128 +
                               ((kc * 64 + (lane >> 4) * 16) ^ ((row & 7) << 4)));
      }
#pragma unroll
      for (int mt = 0; mt < 4; ++mt)
#pragma unroll
        for (int nt = 0; nt < 4; ++nt)
          acc[mt][nt] = __builtin_amdgcn_mfma_f32_16x16x32_f16(af[mt], bh[nt], acc[mt][nt], 0, 0, 0);
    }
  }

  const int rbase = tm * 128 + wm * 64 + (lane >> 4) * 4;
  const int cbase = tn * 128 + wn * 64 + (lane & 15);
#pragma unroll
  for (int mt = 0; mt < 4; ++mt) {
#pragma unroll
    for (int nt = 0; nt < 4; ++nt) {
      int gc = cbase + nt * 16;
      float bv = (flags & GF_BIAS) ? bias[gc] : 0.f;
#pragma unroll
      for (int rg = 0; rg < 4; ++rg) {
        int gr = rbase + mt * 16 + rg;
        if ((flags & GF_GUARDM) && gr >= M) continue;
        Cm[(size_t)gr * ldc + gc] = acc[mt][nt][rg] + bv;
      }
    }
  }
}

// ---------- manual grid barrier (all 64 WGs co-resident: 144KB LDS -> 1 WG/CU)
__device__ __forceinline__ void grid_barrier(unsigned* bar, unsigned target) {
  __threadfence();                    // release: make our stores agent-visible
  __syncthreads();
  if (threadIdx.x == 0) {
    __hip_atomic_fetch_add(bar, 1u, __ATOMIC_RELAXED, __HIP_MEMORY_SCOPE_AGENT);
    while (__hip_atomic_load(bar, __ATOMIC_RELAXED, __HIP_MEMORY_SCOPE_AGENT) < target)
      __builtin_amdgcn_s_sleep(1);
  }
  __syncthreads();
  __threadfence();                    // acquire: drop stale cached lines
}

// ---------- pipelined 2-layer LSTM stack (64 WGs x 256 thr, manual grid sync)
// WGs 0..31: layer0 (input = X embeddings); WGs 32..63: layer1 (input = y0,
// one step behind). Each WG owns 16 hidden units (64 gate rows); its
// [64][1024] fp16 weight slice lives XOR-swizzled in LDS.
struct LstmArgs {
  const short* W0;   // [2048][1024] fp16 [Wih0|Whh0], gate-reordered
  const short* W1;   // [2048][1024] fp16 [Wih1|Whh1]
  const short* X;    // [T][64][512] fp16 embeddings
  const float* b0;   // [2048] fp32 reordered
  const float* b1;
  short* h0;         // history base, slot stride 32768 (slot = [64][512])
  short* h1;
  const float* c0i;  // initial c (null = zeros)
  const float* c1i;
  float* c0o;        // final c out (null = skip)
  float* c1o;
  unsigned* bar;
  int T;
};

__global__ __launch_bounds__(256, 1) void lstm_stack(LstmArgs A) {
  __shared__ short Wlds[64 * 1024];   // 128 KB
  __shared__ float pre[64 * 64];      // 16 KB
  const int tid = threadIdx.x, lane = tid & 63, wave = tid >> 6;
  const int w = blockIdx.x, layer = w >> 5, wl = w & 31;

  // stage weight slice into LDS with XOR swizzle on byte bits 4-6
  const short* Wsrc = (layer ? A.W1 : A.W0) + (size_t)(wl * 64) * 1024;
  for (int i = tid * 8; i < 64 * 1024; i += 256 * 8) {
    int row = i >> 10, k = i & 1023;
    v8s v = *(const v8s*)(Wsrc + (size_t)row * 1024 + k);
    *(v8s*)((char*)Wlds + row * 2048 + ((k * 2) ^ ((row & 7) << 4))) = v;
  }

  const int uu = tid & 15, bq0 = tid >> 4;
  const int j = wl * 16 + uu;          // hidden unit owned by this thread
  const float* bp = (layer ? A.b1 : A.b0) + wl * 64 + uu * 4;
  const float b0v = bp[0], b1v = bp[1], b2v = bp[2], b3v = bp[3];
  float creg[4];
  {
    const float* ci = layer ? A.c1i : A.c0i;
#pragma unroll
    for (int q = 0; q < 4; ++q) {
      int b = q * 16 + bq0;
      creg[q] = ci ? ci[b * 512 + j] : 0.f;
    }
  }
  short* hist = layer ? A.h1 : A.h0;
  __syncthreads();

  const int arow = wave * 16 + (lane & 15);
  const int koff = (lane >> 4) * 8;

  for (int r = 0; r <= A.T; ++r) {
    const int t = layer ? (r - 1) : r;
    const bool active = layer ? (r >= 1) : (r < A.T);
    if (active) {
      const short* s1 = layer ? (A.h0 + (size_t)(t + 1) * 32768)   // y0[t]
                              : (A.X + (size_t)t * 32768);          // x[t]
      const short* s2 = hist + (size_t)t * 32768;                   // own h[t]
      v4f acc[4] = {};
      for (int kc = 0; kc < 32; ++kc) {
        int kg = kc * 32 + koff;
        const short* ap = (kg < 512) ? (s1 + (size_t)arow * 512 + kg)
                                     : (s2 + (size_t)arow * 512 + (kg - 512));
        v8h af = *(const v8h*)ap;
#pragma unroll
        for (int nt = 0; nt < 4; ++nt) {
          int wrow = nt * 16 + (lane & 15);
          v8h bh = *(const v8h*)((const char*)Wlds + wrow * 2048 +
                                 ((kg * 2) ^ ((wrow & 7) << 4)));
          acc[nt] = __builtin_amdgcn_mfma_f32_16x16x32_f16(af, bh, acc[nt], 0, 0, 0);
        }
      }
#pragma unroll
      for (int nt = 0; nt < 4; ++nt)
#pragma unroll
        for (int rg = 0; rg < 4; ++rg)
          pre[(wave * 16 + (lane >> 4) * 4 + rg) * 64 + nt * 16 + (lane & 15)] = acc[nt][rg];
    }
    __syncthreads();
    if (active) {
#pragma unroll
      for (int q = 0; q < 4; ++q) {
        int b = q * 16 + bq0;
        v4f g = *(const v4f*)(&pre[b * 64 + uu * 4]);
        float g0 = g[0] + b0v, g1 = g[1] + b1v, g2 = g[2] + b2v, g3 = g[3] + b3v;
        float c = sigf(g1) * creg[q] + sigf(g0) * tanhfast(g2);
        creg[q] = c;
        float h = sigf(g3) * tanhfast(c);
        hist[(size_t)(t + 1) * 32768 + b * 512 + j] = f2h(h);
      }
    }
    grid_barrier(A.bar, (unsigned)(r + 1) * 64u);
  }

  float* co = layer ? A.c1o : A.c0o;
  if (co) {
#pragma unroll
    for (int q = 0; q < 4; ++q) {
      int b = q * 16 + bq0;
      co[b * 512 + j] = creg[q];
    }
  }
}

extern "C" void kernel_launch(void* const* d_in, const int* in_sizes, int n_in,
                              void* d_out, int out_size, void* d_ws, size_t ws_size,
                              hipStream_t stream) {
  (void)in_sizes; (void)n_in; (void)out_size; (void)ws_size;
  const int* src = (const int*)d_in[0];
  const int* trg = (const int*)d_in[1];
  const float* enc_emb = (const float*)d_in[3];
  const float* dec_emb = (const float*)d_in[4];
  const float* enc_Wih = (const float*)d_in[5];
  const float* enc_Whh = (const float*)d_in[6];
  const float* enc_bih = (const float*)d_in[7];
  const float* enc_bhh = (const float*)d_in[8];
  const float* dec_Wih = (const float*)d_in[9];
  const float* dec_Whh = (const float*)d_in[10];
  const float* dec_bih = (const float*)d_in[11];
  const float* dec_bhh = (const float*)d_in[12];
  const float* out_W = (const float*)d_in[13];
  const float* out_b = (const float*)d_in[14];

  char* p = (char*)d_ws;
  auto alloc = [&](size_t sz) { char* r = p; p += (sz + 255) & ~(size_t)255; return r; };
  const size_t SLOT = 32768;                       // shorts per history slot
  short* H0   = (short*)alloc(257 * SLOT * 2);     // 16.1 MB
  short* H1   = (short*)alloc(257 * SLOT * 2);
  short* encW0 = (short*)alloc((size_t)2048 * 1024 * 2);
  short* encW1 = (short*)alloc((size_t)2048 * 1024 * 2);
  short* decW0 = (short*)alloc((size_t)2048 * 1024 * 2);
  short* decW1 = (short*)alloc((size_t)2048 * 1024 * 2);
  short* outWb = (short*)alloc((size_t)16000 * 512 * 2);
  short* X     = (short*)alloc((size_t)8192 * 512 * 2);
  float* bE0 = (float*)alloc(2048 * 4);
  float* bE1 = (float*)alloc(2048 * 4);
  float* bD0 = (float*)alloc(2048 * 4);
  float* bD1 = (float*)alloc(2048 * 4);
  float* c0buf = (float*)alloc((size_t)64 * 512 * 4);
  float* c1buf = (float*)alloc((size_t)64 * 512 * 4);
  unsigned* bar = (unsigned*)alloc(256);
  // total ~72 MB

  // zero init slots + barrier counters
  zero_k<<<128, 256, 0, stream>>>(H0, 32768);                    // enc h0 init
  zero_k<<<128, 256, 0, stream>>>(H1, 32768);                    // enc h1 init
  zero_k<<<128, 256, 0, stream>>>(H1 + 256 * SLOT, 32768);       // logits pad
  zero_k<<<1, 256, 0, stream>>>((short*)bar, 4);

  // weight conversion / reorder: [Wih | Whh] concat, gate-interleaved rows
  conv_w<<<1024, 256, 0, stream>>>(enc_Wih, encW0, 2048, 1024, 0, 1);
  conv_w<<<1024, 256, 0, stream>>>(enc_Whh, encW0, 2048, 1024, 512, 1);
  conv_w<<<1024, 256, 0, stream>>>(enc_Wih + (size_t)2048 * 512, encW1, 2048, 1024, 0, 1);
  conv_w<<<1024, 256, 0, stream>>>(enc_Whh + (size_t)2048 * 512, encW1, 2048, 1024, 512, 1);
  conv_w<<<1024, 256, 0, stream>>>(dec_Wih, decW0, 2048, 1024, 0, 1);
  conv_w<<<1024, 256, 0, stream>>>(dec_Whh, decW0, 2048, 1024, 512, 1);
  conv_w<<<1024, 256, 0, stream>>>(dec_Wih + (size_t)2048 * 512, decW1, 2048, 1024, 0, 1);
  conv_w<<<1024, 256, 0, stream>>>(dec_Whh + (size_t)2048 * 512, decW1, 2048, 1024, 512, 1);
  conv_w<<<8000, 256, 0, stream>>>(out_W, outWb, 16000, 512, 0, 0);
  conv_b<<<8, 256, 0, stream>>>(enc_bih, enc_bhh, bE0);
  conv_b<<<8, 256, 0, stream>>>(enc_bih + 2048, enc_bhh + 2048, bE1);
  conv_b<<<8, 256, 0, stream>>>(dec_bih, dec_bhh, bD0);
  conv_b<<<8, 256, 0, stream>>>(dec_bih + 2048, dec_bhh + 2048, bD1);

  // encoder
  embed_k<<<8192, 256, 0, stream>>>(src, enc_emb, X, 8192);
  LstmArgs ea = {encW0, encW1, X, bE0, bE1, H0, H1,
                 nullptr, nullptr, c0buf, c1buf, bar, 128};
  lstm_stack<<<64, 256, 0, stream>>>(ea);

  // decoder (histories continue at slot 128 = encoder finals)
  embed_k<<<8192, 256, 0, stream>>>(trg, dec_emb, X, 8128);
  LstmArgs da = {decW0, decW1, X, bD0, bD1, H0 + 128 * SLOT, H1 + 128 * SLOT,
                 c0buf, c1buf, nullptr, nullptr, bar + 1, 127};
  lstm_stack<<<64, 256, 0, stream>>>(da);

  // logits = H1[129..255] @ out_W^T + out_b -> fp32 d_out [8128][16000]
  gemm_bt<<<dim3(125, 64), 256, 0, stream>>>(H1 + 129 * SLOT, outWb, out_b,
                                             (float*)d_out, 8128, 16000, 512, 16000,
                                             GF_BIAS | GF_GUARDM);
}

// Round 3
// 3320.643 us; speedup vs baseline: 1.4641x; 1.4641x over previous
//
#include <hip/hip_runtime.h>

// V=16000 E=512 H=512 L=2 S=128 T=128 B=64; gate dim 4H=2048
// Both LSTM layers do a K=1024 concat GEMM per step:
//   gates[b][4H] = [x_t | h_{t-1}] @ [Wih | Whh]^T + (bih+bhh)
// Histories per layer: 257 slots of [64][512] fp16. Slot g = state at time g:
//   g=0 zeros (enc init), g=1..128 encoder outputs, g=129..255 decoder outputs,
//   slot 256 zero pad for the logits GEMM's 8192-row tile reads.
// Cross-WG coherence: h stores are write-through (sc1), so the grid barrier
// needs no buffer_wbl2; acquire side is one buffer_inv sc1 per wave.

typedef __attribute__((ext_vector_type(8))) short v8s;
typedef __attribute__((ext_vector_type(4))) short v4s;
typedef __attribute__((ext_vector_type(8))) _Float16 v8h;
typedef __attribute__((ext_vector_type(4))) float v4f;

#define AS1 __attribute__((address_space(1)))
#define AS3 __attribute__((address_space(3)))

__device__ __forceinline__ short f2h(float x) {
  _Float16 h = (_Float16)x;
  return __builtin_bit_cast(short, h);
}
__device__ __forceinline__ void gload16(const void* g, void* l) {
  __builtin_amdgcn_global_load_lds((const AS1 void*)g, (AS3 void*)l, 16, 0, 0);
}
__device__ __forceinline__ float sigf(float x) { return 1.f / (1.f + __expf(-x)); }
__device__ __forceinline__ float tanhfast(float x) { return 2.f / (1.f + __expf(-2.f * x)) - 1.f; }

// write-through 2B store (agent-coherent without L2 dirtying)
__device__ __forceinline__ void store2_sc1(void* p, unsigned v) {
  asm volatile("global_store_short %0, %1, off sc1" :: "v"(p), "v"(v) : "memory");
}

// ---------- weight convert fp32->fp16 + gate reorder (i,f,g,o interleave per unit)
__global__ void conv_w(const float* __restrict__ in, short* __restrict__ out,
                       int rows, int ldo, int coloff, int reorder) {
  int i = blockIdx.x * 256 + threadIdx.x;       // one float4 per thread
  if (i >= rows * 128) return;                  // K=512 -> 128 quads per row
  int r = i >> 7, k4 = (i & 127) * 4;
  int rr = reorder ? ((r & 511) * 4 + (r >> 9)) : r;
  float4 v = *(const float4*)(in + (size_t)r * 512 + k4);
  v4s s; s[0] = f2h(v.x); s[1] = f2h(v.y); s[2] = f2h(v.z); s[3] = f2h(v.w);
  *(v4s*)(out + (size_t)rr * ldo + coloff + k4) = s;
}

__global__ void conv_b(const float* __restrict__ a, const float* __restrict__ b,
                       float* __restrict__ o) {
  int r = blockIdx.x * 256 + threadIdx.x;
  if (r < 2048) o[(r & 511) * 4 + (r >> 9)] = a[r] + b[r];
}

// ---------- embedding gather to fp16, rows >= nvalid get zeros
__global__ void embed_k(const int* __restrict__ ids, const float* __restrict__ emb,
                        short* __restrict__ out, int nvalid) {
  int row = blockIdx.x;
  int e = threadIdx.x * 2;
  float2 v = make_float2(0.f, 0.f);
  if (row < nvalid) {
    int id = ids[row];
    v = *(const float2*)(emb + (size_t)id * 512 + e);
  }
  unsigned pack = ((unsigned)(unsigned short)f2h(v.y) << 16) | (unsigned short)f2h(v.x);
  *(unsigned*)(out + (size_t)row * 512 + e) = pack;
}

__global__ void zero_k(short* p, int n) {
  int i = blockIdx.x * 256 + threadIdx.x;
  if (i < n) p[i] = 0;
}

// ---------- GEMM: C[M,N] = A[M,K] * B[N,K]^T (+bias), 128x128 tile, BK=64, fp16
#define GF_BIAS 2
#define GF_GUARDM 4

__global__ __launch_bounds__(256, 2) void gemm_bt(
    const short* __restrict__ Am, const short* __restrict__ Bm,
    const float* __restrict__ bias, float* __restrict__ Cm,
    int M, int N, int K, int ldc, int flags) {
  __shared__ short lA[128 * 64];
  __shared__ short lB[128 * 64];
  const int tid = threadIdx.x, lane = tid & 63, wave = tid >> 6;
  const int wm = wave >> 1, wn = wave & 1;
  const int tm = blockIdx.y, tn = blockIdx.x;
  v4f acc[4][4] = {};
  const short* Abase = Am + (size_t)tm * 128 * K;
  const short* Bbase = Bm + (size_t)tn * 128 * K;

  for (int kt = 0; kt < K; kt += 64) {
    __syncthreads();
#pragma unroll
    for (int i2 = 0; i2 < 4; ++i2) {
      int c = (wave * 4 + i2) * 64 + lane;    // 16B chunk id, 1024 per tile
      int row = c >> 3, ch = c & 7;
      int sch = ch ^ (row & 7);               // inverse swizzle on global source
      gload16(Abase + (size_t)row * K + kt + sch * 8, (char*)lA + (wave * 4 + i2) * 1024);
      gload16(Bbase + (size_t)row * K + kt + sch * 8, (char*)lB + (wave * 4 + i2) * 1024);
    }
    asm volatile("s_waitcnt vmcnt(0)" ::: "memory");
    __syncthreads();
#pragma unroll
    for (int kc = 0; kc < 2; ++kc) {
      v8h af[4], bh[4];
#pragma unroll
      for (int mt = 0; mt < 4; ++mt) {
        int row = wm * 64 + mt * 16 + (lane & 15);
        af[mt] = *(const v8h*)((const char*)lA + row * 128 +
                               ((kc * 64 + (lane >> 4) * 16) ^ ((row & 7) << 4)));
      }
#pragma unroll
      for (int nt = 0; nt < 4; ++nt) {
        int row = wn * 64 + nt * 16 + (lane & 15);
        bh[nt] = *(const v8h*)((const char*)lB + row * 128 +
                               ((kc * 64 + (lane >> 4) * 16) ^ ((row & 7) << 4)));
      }
#pragma unroll
      for (int mt = 0; mt < 4; ++mt)
#pragma unroll
        for (int nt = 0; nt < 4; ++nt)
          acc[mt][nt] = __builtin_amdgcn_mfma_f32_16x16x32_f16(af[mt], bh[nt], acc[mt][nt], 0, 0, 0);
    }
  }

  const int rbase = tm * 128 + wm * 64 + (lane >> 4) * 4;
  const int cbase = tn * 128 + wn * 64 + (lane & 15);
#pragma unroll
  for (int mt = 0; mt < 4; ++mt) {
#pragma unroll
    for (int nt = 0; nt < 4; ++nt) {
      int gc = cbase + nt * 16;
      float bv = (flags & GF_BIAS) ? bias[gc] : 0.f;
#pragma unroll
      for (int rg = 0; rg < 4; ++rg) {
        int gr = rbase + mt * 16 + rg;
        if ((flags & GF_GUARDM) && gr >= M) continue;
        Cm[(size_t)gr * ldc + gc] = acc[mt][nt][rg] + bv;
      }
    }
  }
}

// ---------- manual grid barrier (all 64 WGs co-resident: ~146KB LDS -> 1 WG/CU)
// Release: h stores are sc1 write-through, so vmcnt(0) makes them agent-visible;
// no buffer_wbl2 needed. Acquire: buffer_inv sc1 per wave (clang's acquire fence).
__device__ __forceinline__ void grid_barrier(unsigned* bar, unsigned target) {
  asm volatile("s_waitcnt vmcnt(0)" ::: "memory");
  __syncthreads();
  if (threadIdx.x == 0) {
    __hip_atomic_fetch_add(bar, 1u, __ATOMIC_RELAXED, __HIP_MEMORY_SCOPE_AGENT);
    while (__hip_atomic_load(bar, __ATOMIC_RELAXED, __HIP_MEMORY_SCOPE_AGENT) < target)
      __builtin_amdgcn_s_sleep(1);
  }
  __syncthreads();
  asm volatile("s_waitcnt vmcnt(0) lgkmcnt(0)\n\tbuffer_inv sc1" ::: "memory");
}

// ---------- pipelined 2-layer LSTM stack (64 WGs x 256 thr, manual grid sync)
// WGs 0..31: layer0 (input = X embeddings); WGs 32..63: layer1 (input = y0,
// one step behind). Each WG owns 16 hidden units (64 gate rows); its
// [64][1024] fp16 weight slice lives XOR-swizzled in LDS.
struct LstmArgs {
  const short* W0;   // [2048][1024] fp16 [Wih0|Whh0], gate-reordered
  const short* W1;   // [2048][1024] fp16 [Wih1|Whh1]
  const short* X;    // [T][64][512] fp16 embeddings
  const float* b0;   // [2048] fp32 reordered
  const float* b1;
  short* h0;         // history base, slot stride 32768 (slot = [64][512])
  short* h1;
  const float* c0i;  // initial c (null = zeros)
  const float* c1i;
  float* c0o;        // final c out (null = skip)
  float* c1o;
  unsigned* bar;
  int T;
};

#define PRE_LD 72   // padded row stride (floats) for pre[] to cut bank conflicts

__global__ __launch_bounds__(256, 1) void lstm_stack(LstmArgs A) {
  __shared__ short Wlds[64 * 1024];     // 128 KB
  __shared__ float pre[64 * PRE_LD];    // 18 KB
  const int tid = threadIdx.x, lane = tid & 63, wave = tid >> 6;
  const int w = blockIdx.x, layer = w >> 5, wl = w & 31;

  // stage weight slice into LDS with XOR swizzle on byte bits 4-6
  const short* Wsrc = (layer ? A.W1 : A.W0) + (size_t)(wl * 64) * 1024;
  for (int i = tid * 8; i < 64 * 1024; i += 256 * 8) {
    int row = i >> 10, k = i & 1023;
    v8s v = *(const v8s*)(Wsrc + (size_t)row * 1024 + k);
    *(v8s*)((char*)Wlds + row * 2048 + ((k * 2) ^ ((row & 7) << 4))) = v;
  }

  const int uu = tid & 15, bq0 = tid >> 4;
  const int j = wl * 16 + uu;          // hidden unit owned by this thread
  const float* bp = (layer ? A.b1 : A.b0) + wl * 64 + uu * 4;
  const float b0v = bp[0], b1v = bp[1], b2v = bp[2], b3v = bp[3];
  float creg[4];
  {
    const float* ci = layer ? A.c1i : A.c0i;
#pragma unroll
    for (int q = 0; q < 4; ++q) {
      int b = q * 16 + bq0;
      creg[q] = ci ? ci[b * 512 + j] : 0.f;
    }
  }
  short* hist = layer ? A.h1 : A.h0;
  __syncthreads();

  const int arow = wave * 16 + (lane & 15);
  const int koff = (lane >> 4) * 8;

  for (int r = 0; r <= A.T; ++r) {
    const int t = layer ? (r - 1) : r;
    const bool active = layer ? (r >= 1) : (r < A.T);
    if (active) {
      const short* s1 = layer ? (A.h0 + (size_t)(t + 1) * 32768)   // y0[t]
                              : (A.X + (size_t)t * 32768);          // x[t]
      const short* s2 = hist + (size_t)t * 32768;                   // own h[t]
      v4f acc[4] = {};
      for (int kc = 0; kc < 32; ++kc) {
        int kg = kc * 32 + koff;
        const short* ap = (kg < 512) ? (s1 + (size_t)arow * 512 + kg)
                                     : (s2 + (size_t)arow * 512 + (kg - 512));
        v8h af = *(const v8h*)ap;
#pragma unroll
        for (int nt = 0; nt < 4; ++nt) {
          int wrow = nt * 16 + (lane & 15);
          v8h bh = *(const v8h*)((const char*)Wlds + wrow * 2048 +
                                 ((kg * 2) ^ ((wrow & 7) << 4)));
          acc[nt] = __builtin_amdgcn_mfma_f32_16x16x32_f16(af, bh, acc[nt], 0, 0, 0);
        }
      }
#pragma unroll
      for (int nt = 0; nt < 4; ++nt)
#pragma unroll
        for (int rg = 0; rg < 4; ++rg)
          pre[(wave * 16 + (lane >> 4) * 4 + rg) * PRE_LD + nt * 16 + (lane & 15)] = acc[nt][rg];
    }
    __syncthreads();
    if (active) {
#pragma unroll
      for (int q = 0; q < 4; ++q) {
        int b = q * 16 + bq0;
        v4f g = *(const v4f*)(&pre[b * PRE_LD + uu * 4]);
        float g0 = g[0] + b0v, g1 = g[1] + b1v, g2 = g[2] + b2v, g3 = g[3] + b3v;
        float c = sigf(g1) * creg[q] + sigf(g0) * tanhfast(g2);
        creg[q] = c;
        float h = sigf(g3) * tanhfast(c);
        unsigned hv = (unsigned)(unsigned short)f2h(h);
        store2_sc1(hist + (size_t)(t + 1) * 32768 + b * 512 + j, hv);
      }
    }
    grid_barrier(A.bar, (unsigned)(r + 1) * 64u);
  }

  float* co = layer ? A.c1o : A.c0o;
  if (co) {
#pragma unroll
    for (int q = 0; q < 4; ++q) {
      int b = q * 16 + bq0;
      co[b * 512 + j] = creg[q];
    }
  }
}

extern "C" void kernel_launch(void* const* d_in, const int* in_sizes, int n_in,
                              void* d_out, int out_size, void* d_ws, size_t ws_size,
                              hipStream_t stream) {
  (void)in_sizes; (void)n_in; (void)out_size; (void)ws_size;
  const int* src = (const int*)d_in[0];
  const int* trg = (const int*)d_in[1];
  const float* enc_emb = (const float*)d_in[3];
  const float* dec_emb = (const float*)d_in[4];
  const float* enc_Wih = (const float*)d_in[5];
  const float* enc_Whh = (const float*)d_in[6];
  const float* enc_bih = (const float*)d_in[7];
  const float* enc_bhh = (const float*)d_in[8];
  const float* dec_Wih = (const float*)d_in[9];
  const float* dec_Whh = (const float*)d_in[10];
  const float* dec_bih = (const float*)d_in[11];
  const float* dec_bhh = (const float*)d_in[12];
  const float* out_W = (const float*)d_in[13];
  const float* out_b = (const float*)d_in[14];

  char* p = (char*)d_ws;
  auto alloc = [&](size_t sz) { char* r = p; p += (sz + 255) & ~(size_t)255; return r; };
  const size_t SLOT = 32768;                       // shorts per history slot
  short* H0   = (short*)alloc(257 * SLOT * 2);     // 16.1 MB
  short* H1   = (short*)alloc(257 * SLOT * 2);
  short* encW0 = (short*)alloc((size_t)2048 * 1024 * 2);
  short* encW1 = (short*)alloc((size_t)2048 * 1024 * 2);
  short* decW0 = (short*)alloc((size_t)2048 * 1024 * 2);
  short* decW1 = (short*)alloc((size_t)2048 * 1024 * 2);
  short* outWb = (short*)alloc((size_t)16000 * 512 * 2);
  short* X     = (short*)alloc((size_t)8192 * 512 * 2);
  float* bE0 = (float*)alloc(2048 * 4);
  float* bE1 = (float*)alloc(2048 * 4);
  float* bD0 = (float*)alloc(2048 * 4);
  float* bD1 = (float*)alloc(2048 * 4);
  float* c0buf = (float*)alloc((size_t)64 * 512 * 4);
  float* c1buf = (float*)alloc((size_t)64 * 512 * 4);
  unsigned* bar = (unsigned*)alloc(256);
  // total ~72 MB

  // zero init slots + barrier counters
  zero_k<<<128, 256, 0, stream>>>(H0, 32768);                    // enc h0 init
  zero_k<<<128, 256, 0, stream>>>(H1, 32768);                    // enc h1 init
  zero_k<<<128, 256, 0, stream>>>(H1 + 256 * SLOT, 32768);       // logits pad
  zero_k<<<1, 256, 0, stream>>>((short*)bar, 4);

  // weight conversion / reorder: [Wih | Whh] concat, gate-interleaved rows
  conv_w<<<1024, 256, 0, stream>>>(enc_Wih, encW0, 2048, 1024, 0, 1);
  conv_w<<<1024, 256, 0, stream>>>(enc_Whh, encW0, 2048, 1024, 512, 1);
  conv_w<<<1024, 256, 0, stream>>>(enc_Wih + (size_t)2048 * 512, encW1, 2048, 1024, 0, 1);
  conv_w<<<1024, 256, 0, stream>>>(enc_Whh + (size_t)2048 * 512, encW1, 2048, 1024, 512, 1);
  conv_w<<<1024, 256, 0, stream>>>(dec_Wih, decW0, 2048, 1024, 0, 1);
  conv_w<<<1024, 256, 0, stream>>>(dec_Whh, decW0, 2048, 1024, 512, 1);
  conv_w<<<1024, 256, 0, stream>>>(dec_Wih + (size_t)2048 * 512, decW1, 2048, 1024, 0, 1);
  conv_w<<<1024, 256, 0, stream>>>(dec_Whh + (size_t)2048 * 512, decW1, 2048, 1024, 512, 1);
  conv_w<<<8000, 256, 0, stream>>>(out_W, outWb, 16000, 512, 0, 0);
  conv_b<<<8, 256, 0, stream>>>(enc_bih, enc_bhh, bE0);
  conv_b<<<8, 256, 0, stream>>>(enc_bih + 2048, enc_bhh + 2048, bE1);
  conv_b<<<8, 256, 0, stream>>>(dec_bih, dec_bhh, bD0);
  conv_b<<<8, 256, 0, stream>>>(dec_bih + 2048, dec_bhh + 2048, bD1);

  // encoder
  embed_k<<<8192, 256, 0, stream>>>(src, enc_emb, X, 8192);
  LstmArgs ea = {encW0, encW1, X, bE0, bE1, H0, H1,
                 nullptr, nullptr, c0buf, c1buf, bar, 128};
  lstm_stack<<<64, 256, 0, stream>>>(ea);

  // decoder (histories continue at slot 128 = encoder finals)
  embed_k<<<8192, 256, 0, stream>>>(trg, dec_emb, X, 8128);
  LstmArgs da = {decW0, decW1, X, bD0, bD1, H0 + 128 * SLOT, H1 + 128 * SLOT,
                 c0buf, c1buf, nullptr, nullptr, bar + 1, 127};
  lstm_stack<<<64, 256, 0, stream>>>(da);

  // logits = H1[129..255] @ out_W^T + out_b -> fp32 d_out [8128][16000]
  gemm_bt<<<dim3(125, 64), 256, 0, stream>>>(H1 + 129 * SLOT, outWb, out_b,
                                             (float*)d_out, 8128, 16000, 512, 16000,
                                             GF_BIAS | GF_GUARDM);
}

// Round 6
// 3182.682 us; speedup vs baseline: 1.5275x; 1.0433x over previous
//
#include <hip/hip_runtime.h>

// V=16000 E=512 H=512 L=2 S=128 T=128 B=64; gate dim 4H=2048
// One fused recurrence kernel, lockstep rounds r=0..255. Layer 0 (WGs 0..31)
// computes step g=r (active r<255); layer 1 (WGs 32..63) computes g=r-1
// (active r>=1). Both layers: K=1024 concat GEMM [x|h]@[Wih|Whh]^T + bias.
// Layer-0 h history = 2-slot ring (parity of state index); layer-1 h history
// = full 257 slots (slot s = state after s steps; 129..255 feed the logits
// GEMM, slot 256 = zero pad). X holds enc (rows 0..8191) + dec (8192..16319)
// embeddings, slot stride 32768 shorts. Weight slices live XOR-swizzled in
// LDS; each WG reloads its dec slice once at its phase switch.
// WS budget ~65 MB (<=72 MB proven safe; >=140 MB failed = overflow).

typedef __attribute__((ext_vector_type(8))) short v8s;
typedef __attribute__((ext_vector_type(4))) short v4s;
typedef __attribute__((ext_vector_type(8))) _Float16 v8h;
typedef __attribute__((ext_vector_type(4))) float v4f;
typedef __attribute__((ext_vector_type(4))) unsigned int v4u;

#define AS1 __attribute__((address_space(1)))
#define AS3 __attribute__((address_space(3)))

__device__ __forceinline__ short f2h(float x) {
  _Float16 h = (_Float16)x;
  return __builtin_bit_cast(short, h);
}
__device__ __forceinline__ void gload16(const void* g, void* l) {
  __builtin_amdgcn_global_load_lds((const AS1 void*)g, (AS3 void*)l, 16, 0, 0);
}
__device__ __forceinline__ float sigf(float x) { return 1.f / (1.f + __expf(-x)); }
__device__ __forceinline__ float tanhfast(float x) { return 2.f / (1.f + __expf(-2.f * x)) - 1.f; }

// ---------- weight convert fp32->fp16 + gate reorder (i,f,g,o interleave per unit)
__global__ void conv_w(const float* __restrict__ in, short* __restrict__ out,
                       int rows, int ldo, int coloff, int reorder) {
  int i = blockIdx.x * 256 + threadIdx.x;       // one float4 per thread
  if (i >= rows * 128) return;                  // K=512 -> 128 quads per row
  int r = i >> 7, k4 = (i & 127) * 4;
  int rr = reorder ? ((r & 511) * 4 + (r >> 9)) : r;
  float4 v = *(const float4*)(in + (size_t)r * 512 + k4);
  v4s s; s[0] = f2h(v.x); s[1] = f2h(v.y); s[2] = f2h(v.z); s[3] = f2h(v.w);
  *(v4s*)(out + (size_t)rr * ldo + coloff + k4) = s;
}

__global__ void conv_b(const float* __restrict__ a, const float* __restrict__ b,
                       float* __restrict__ o) {
  int r = blockIdx.x * 256 + threadIdx.x;
  if (r < 2048) o[(r & 511) * 4 + (r >> 9)] = a[r] + b[r];
}

// ---------- embedding gather to fp16, rows >= nvalid get zeros
__global__ void embed_k(const int* __restrict__ ids, const float* __restrict__ emb,
                        short* __restrict__ out, int nvalid) {
  int row = blockIdx.x;
  int e = threadIdx.x * 2;
  float2 v = make_float2(0.f, 0.f);
  if (row < nvalid) {
    int id = ids[row];
    v = *(const float2*)(emb + (size_t)id * 512 + e);
  }
  unsigned pack = ((unsigned)(unsigned short)f2h(v.y) << 16) | (unsigned short)f2h(v.x);
  *(unsigned*)(out + (size_t)row * 512 + e) = pack;
}

__global__ void zero_k(short* p, int n) {
  int i = blockIdx.x * 256 + threadIdx.x;
  if (i < n) p[i] = 0;
}

// ---------- GEMM: C[M,N] = A[M,K] * B[N,K]^T (+bias), 128x128 tile, BK=64, fp16
#define GF_BIAS 2
#define GF_GUARDM 4

__global__ __launch_bounds__(256, 2) void gemm_bt(
    const short* __restrict__ Am, const short* __restrict__ Bm,
    const float* __restrict__ bias, float* __restrict__ Cm,
    int M, int N, int K, int ldc, int flags) {
  __shared__ short lA[128 * 64];
  __shared__ short lB[128 * 64];
  const int tid = threadIdx.x, lane = tid & 63, wave = tid >> 6;
  const int wm = wave >> 1, wn = wave & 1;
  const int tm = blockIdx.y, tn = blockIdx.x;
  v4f acc[4][4] = {};
  const short* Abase = Am + (size_t)tm * 128 * K;
  const short* Bbase = Bm + (size_t)tn * 128 * K;

  for (int kt = 0; kt < K; kt += 64) {
    __syncthreads();
#pragma unroll
    for (int i2 = 0; i2 < 4; ++i2) {
      int c = (wave * 4 + i2) * 64 + lane;    // 16B chunk id, 1024 per tile
      int row = c >> 3, ch = c & 7;
      int sch = ch ^ (row & 7);               // inverse swizzle on global source
      gload16(Abase + (size_t)row * K + kt + sch * 8, (char*)lA + (wave * 4 + i2) * 1024);
      gload16(Bbase + (size_t)row * K + kt + sch * 8, (char*)lB + (wave * 4 + i2) * 1024);
    }
    asm volatile("s_waitcnt vmcnt(0)" ::: "memory");
    __syncthreads();
#pragma unroll
    for (int kc = 0; kc < 2; ++kc) {
      v8h af[4], bh[4];
#pragma unroll
      for (int mt = 0; mt < 4; ++mt) {
        int row = wm * 64 + mt * 16 + (lane & 15);
        af[mt] = *(const v8h*)((const char*)lA + row * 128 +
                               ((kc * 64 + (lane >> 4) * 16) ^ ((row & 7) << 4)));
      }
#pragma unroll
      for (int nt = 0; nt < 4; ++nt) {
        int row = wn * 64 + nt * 16 + (lane & 15);
        bh[nt] = *(const v8h*)((const char*)lB + row * 128 +
                               ((kc * 64 + (lane >> 4) * 16) ^ ((row & 7) << 4)));
      }
#pragma unroll
      for (int mt = 0; mt < 4; ++mt)
#pragma unroll
        for (int nt = 0; nt < 4; ++nt)
          acc[mt][nt] = __builtin_amdgcn_mfma_f32_16x16x32_f16(af[mt], bh[nt], acc[mt][nt], 0, 0, 0);
    }
  }

  const int rbase = tm * 128 + wm * 64 + (lane >> 4) * 4;
  const int cbase = tn * 128 + wn * 64 + (lane & 15);
#pragma unroll
  for (int mt = 0; mt < 4; ++mt) {
#pragma unroll
    for (int nt = 0; nt < 4; ++nt) {
      int gc = cbase + nt * 16;
      float bv = (flags & GF_BIAS) ? bias[gc] : 0.f;
#pragma unroll
      for (int rg = 0; rg < 4; ++rg) {
        int gr = rbase + mt * 16 + rg;
        if ((flags & GF_GUARDM) && gr >= M) continue;
        Cm[(size_t)gr * ldc + gc] = acc[mt][nt][rg] + bv;
      }
    }
  }
}

// ---------- fused 2-layer enc+dec LSTM pipeline, lockstep rounds
struct PipeArgs {
  const short* W0e;  // [2048][1024] fp16 [Wih|Whh] gate-reordered, layer0 enc
  const short* W0d;  // layer0 dec
  const short* W1e;  // layer1 enc
  const short* W1d;  // layer1 dec
  const short* X;    // [255 slots][64][512] fp16 embeddings (slot g = x_g)
  const float* b0e;  // [2048] fp32 reordered biases
  const float* b0d;
  const float* b1e;
  const float* b1d;
  short* h0ring;     // 2 slots (state-index parity)
  short* h1;         // 257 slots
  unsigned* flags;   // [64] per-WG round flags
  int Tenc, Ttot;    // 128, 255
};

#define PRE_LD 72
#define SLOT 32768

__global__ __launch_bounds__(256, 1) void lstm_pipe(PipeArgs A) {
  __shared__ __align__(16) short Wlds[64 * 1024];   // 128 KB
  __shared__ __align__(16) float pre[64 * PRE_LD];  // 18 KB
  __shared__ __align__(16) short hsm[64 * 16];      // 2 KB
  const int tid = threadIdx.x, lane = tid & 63, wave = tid >> 6;
  const int w = blockIdx.x, layer = w >> 5, wl = w & 31;

  // stage a [64][1024] weight slice into LDS (XOR swizzle on byte bits 4..6)
  auto stage = [&](const short* Wsrc) {
    for (int i = tid * 8; i < 64 * 1024; i += 256 * 8) {
      int row = i >> 10, k = i & 1023;
      v8s v = *(const v8s*)(Wsrc + (size_t)row * 1024 + k);
      *(v8s*)((char*)Wlds + row * 2048 + ((k * 2) ^ ((row & 7) << 4))) = v;
    }
  };
  stage((layer ? A.W1e : A.W0e) + (size_t)(wl * 64) * 1024);

  const int uu = tid & 15, bq0 = tid >> 4;
  const float* bpe = (layer ? A.b1e : A.b0e) + wl * 64 + uu * 4;
  const float* bpd = (layer ? A.b1d : A.b0d) + wl * 64 + uu * 4;
  const float be0 = bpe[0], be1 = bpe[1], be2 = bpe[2], be3 = bpe[3];
  const float bd0 = bpd[0], bd1 = bpd[1], bd2 = bpd[2], bd3 = bpd[3];
  float creg[4] = {0.f, 0.f, 0.f, 0.f};

  const int arow = wave * 16 + (lane & 15);
  const int koff = (lane >> 4) * 8;
  __syncthreads();

  const int R = A.Ttot + 1;   // 256 rounds
  for (int r = 0; r < R; ++r) {
    // phase-switch weight reloads (WG-uniform conditions)
    if (!layer && r == A.Tenc) {            // layer0 first dec step is g=128=r
      stage(A.W0d + (size_t)(wl * 64) * 1024);
      __syncthreads();
    }
    if (layer && r == A.Tenc + 1) {         // layer1 first dec step at r=129
      stage(A.W1d + (size_t)(wl * 64) * 1024);
      __syncthreads();
    }

    const int g = layer ? (r - 1) : r;
    const bool active = layer ? (r >= 1) : (r < A.Ttot);

    if (active) {
      // K=1024 concat GEMM: gates = [x_or_y0 | h_prev] @ W^T
      const short* s1 = layer ? (A.h0ring + (size_t)((g + 1) & 1) * SLOT)  // y0[g]
                              : (A.X + (size_t)g * SLOT);                   // x[g]
      const short* s2 = layer ? (A.h1 + (size_t)g * SLOT)                   // h1[g]
                              : (A.h0ring + (size_t)(g & 1) * SLOT);        // h0[g]
      v4f acc[4] = {};
      for (int kc = 0; kc < 32; ++kc) {
        int kg = kc * 32 + koff;
        const short* ap = (kg < 512) ? (s1 + (size_t)arow * 512 + kg)
                                     : (s2 + (size_t)arow * 512 + (kg - 512));
        v8h af = *(const v8h*)ap;
#pragma unroll
        for (int nt = 0; nt < 4; ++nt) {
          int wrow = nt * 16 + (lane & 15);
          v8h bh = *(const v8h*)((const char*)Wlds + wrow * 2048 +
                                 ((kg * 2) ^ ((wrow & 7) << 4)));
          acc[nt] = __builtin_amdgcn_mfma_f32_16x16x32_f16(af, bh, acc[nt], 0, 0, 0);
        }
      }
#pragma unroll
      for (int nt = 0; nt < 4; ++nt)
#pragma unroll
        for (int rg = 0; rg < 4; ++rg)
          pre[(wave * 16 + (lane >> 4) * 4 + rg) * PRE_LD + nt * 16 + (lane & 15)] = acc[nt][rg];
    }
    __syncthreads();
    if (active) {
      const bool enc = g < A.Tenc;
#pragma unroll
      for (int q = 0; q < 4; ++q) {
        int b = q * 16 + bq0;
        v4f gv = *(const v4f*)(&pre[b * PRE_LD + uu * 4]);
        float g0 = gv[0] + (enc ? be0 : bd0);
        float g1 = gv[1] + (enc ? be1 : bd1);
        float g2 = gv[2] + (enc ? be2 : bd2);
        float g3 = gv[3] + (enc ? be3 : bd3);
        float c = sigf(g1) * creg[q] + sigf(g0) * tanhfast(g2);
        creg[q] = c;
        float h = sigf(g3) * tanhfast(c);
        hsm[b * 16 + uu] = f2h(h);
      }
      __syncthreads();
      // publish h state g+1: 16B write-through stores
      if (tid < 128) {
        int b = tid >> 1, half = tid & 1;
        v4u d = *(const v4u*)(&hsm[b * 16 + half * 8]);
        short* dst = (layer ? (A.h1 + (size_t)(g + 1) * SLOT)
                            : (A.h0ring + (size_t)((g + 1) & 1) * SLOT))
                     + b * 512 + wl * 16 + half * 8;
        asm volatile("global_store_dwordx4 %0, %1, off sc1" :: "v"(dst), "v"(d) : "memory");
      }
      asm volatile("s_waitcnt vmcnt(0)" ::: "memory");
    }
    __syncthreads();

    // lockstep barrier (skip after final round)
    if (r < R - 1) {
      if (tid == 0)
        __hip_atomic_store(&A.flags[w], (unsigned)(r + 1), __ATOMIC_RELAXED,
                           __HIP_MEMORY_SCOPE_AGENT);
      if (wave == 0) {
        const unsigned tgt = (unsigned)(r + 1);
        unsigned v;
        do {
          v = __hip_atomic_load(&A.flags[lane], __ATOMIC_RELAXED,
                                __HIP_MEMORY_SCOPE_AGENT);
        } while (!__all((int)(v >= tgt)));
      }
      __syncthreads();
      asm volatile("s_waitcnt vmcnt(0) lgkmcnt(0)\n\tbuffer_inv sc1" ::: "memory");
    }
  }
}

extern "C" void kernel_launch(void* const* d_in, const int* in_sizes, int n_in,
                              void* d_out, int out_size, void* d_ws, size_t ws_size,
                              hipStream_t stream) {
  (void)in_sizes; (void)n_in; (void)out_size; (void)ws_size;
  const int* src = (const int*)d_in[0];
  const int* trg = (const int*)d_in[1];
  const float* enc_emb = (const float*)d_in[3];
  const float* dec_emb = (const float*)d_in[4];
  const float* enc_Wih = (const float*)d_in[5];
  const float* enc_Whh = (const float*)d_in[6];
  const float* enc_bih = (const float*)d_in[7];
  const float* enc_bhh = (const float*)d_in[8];
  const float* dec_Wih = (const float*)d_in[9];
  const float* dec_Whh = (const float*)d_in[10];
  const float* dec_bih = (const float*)d_in[11];
  const float* dec_bhh = (const float*)d_in[12];
  const float* out_W = (const float*)d_in[13];
  const float* out_b = (const float*)d_in[14];

  char* p = (char*)d_ws;
  auto alloc = [&](size_t sz) { char* r = p; p += (sz + 255) & ~(size_t)255; return r; };
  short* H1 = (short*)alloc((size_t)257 * SLOT * 2);       // 16.84 MB
  short* H0r = (short*)alloc((size_t)2 * SLOT * 2);        // 128 KB ring
  short* W0e = (short*)alloc((size_t)2048 * 1024 * 2);     // 4 MB each
  short* W0d = (short*)alloc((size_t)2048 * 1024 * 2);
  short* W1e = (short*)alloc((size_t)2048 * 1024 * 2);
  short* W1d = (short*)alloc((size_t)2048 * 1024 * 2);
  short* outWb = (short*)alloc((size_t)16000 * 512 * 2);   // 15.63 MB
  short* X = (short*)alloc((size_t)16384 * 512 * 2);       // 16 MB
  float* bE0 = (float*)alloc(2048 * 4);
  float* bE1 = (float*)alloc(2048 * 4);
  float* bD0 = (float*)alloc(2048 * 4);
  float* bD1 = (float*)alloc(2048 * 4);
  unsigned* flags = (unsigned*)alloc(256);
  // total ~64.7 MB (<= 72 MB proven safe)

  // zero: h0 ring slot 0, h1 slot 0, h1 pad slot 256, flags
  zero_k<<<128, 256, 0, stream>>>(H0r, 32768);
  zero_k<<<128, 256, 0, stream>>>(H1, 32768);
  zero_k<<<128, 256, 0, stream>>>(H1 + (size_t)256 * SLOT, 32768);
  zero_k<<<1, 256, 0, stream>>>((short*)flags, 128);

  // weight conversion / reorder: [Wih | Whh] concat, gate-interleaved rows
  conv_w<<<1024, 256, 0, stream>>>(enc_Wih, W0e, 2048, 1024, 0, 1);
  conv_w<<<1024, 256, 0, stream>>>(enc_Whh, W0e, 2048, 1024, 512, 1);
  conv_w<<<1024, 256, 0, stream>>>(dec_Wih, W0d, 2048, 1024, 0, 1);
  conv_w<<<1024, 256, 0, stream>>>(dec_Whh, W0d, 2048, 1024, 512, 1);
  conv_w<<<1024, 256, 0, stream>>>(enc_Wih + (size_t)2048 * 512, W1e, 2048, 1024, 0, 1);
  conv_w<<<1024, 256, 0, stream>>>(enc_Whh + (size_t)2048 * 512, W1e, 2048, 1024, 512, 1);
  conv_w<<<1024, 256, 0, stream>>>(dec_Wih + (size_t)2048 * 512, W1d, 2048, 1024, 0, 1);
  conv_w<<<1024, 256, 0, stream>>>(dec_Whh + (size_t)2048 * 512, W1d, 2048, 1024, 512, 1);
  conv_w<<<8000, 256, 0, stream>>>(out_W, outWb, 16000, 512, 0, 0);
  conv_b<<<8, 256, 0, stream>>>(enc_bih, enc_bhh, bE0);
  conv_b<<<8, 256, 0, stream>>>(enc_bih + 2048, enc_bhh + 2048, bE1);
  conv_b<<<8, 256, 0, stream>>>(dec_bih, dec_bhh, bD0);
  conv_b<<<8, 256, 0, stream>>>(dec_bih + 2048, dec_bhh + 2048, bD1);

  // embeddings: enc -> X slots 0..127, dec -> X slots 128..254 (pad zeroed)
  embed_k<<<8192, 256, 0, stream>>>(src, enc_emb, X, 8192);
  embed_k<<<8192, 256, 0, stream>>>(trg, dec_emb, X + (size_t)8192 * 512, 8128);

  // fused encoder+decoder recurrence (lockstep)
  PipeArgs pa = {W0e, W0d, W1e, W1d, X, bE0, bD0, bE1, bD1,
                 H0r, H1, flags, 128, 255};
  lstm_pipe<<<64, 256, 0, stream>>>(pa);

  // logits = H1 slots 129..255 (+pad) @ out_W^T + out_b -> fp32 d_out
  gemm_bt<<<dim3(125, 64), 256, 0, stream>>>(H1 + (size_t)129 * SLOT, outWb, out_b,
                                             (float*)d_out, 8128, 16000, 512, 16000,
                                             GF_BIAS | GF_GUARDM);
}